// Round 3
// baseline (222.257 us; speedup 1.0000x reference)
//
#include <hip/hip_runtime.h>
#include <math.h>

// Problem: B=16, N=2049, C=1024, w_qkv is (1024, 3072) row-major.
// out = softmax over n of  scale * (x[b,0,:] @ Wq) . (x[b,n+1,:] @ Wk)
// Reassociated: q_cls[b] = Wq^T x[b,0,:];  v[b] = Wk @ q_cls[b];
//               logit[b,n] = scale * x[b,n+1,:] . v[b]
// Dominant cost: streaming x once (134 MB) in the logits kernel -> HBM roofline ~21 us.

#define BATCH 16
#define SEQ   2049
#define CH    1024
#define W3    3072
#define NOUT  2048

// ws layout (floats):
//   part   : [0, 64*16*1024)        = 4 MB   (q_cls partials over 64 d-chunks)
//   qcls   : [1048576, +16384)      = 64 KB
//   v      : [1064960, +16384)      = 64 KB
//   logits : [1081344, +32768)      = 128 KB

// ---------------- Kernel A: q_cls partials ----------------
// grid (4 colchunks, 64 dchunks), block = 64 (one wave).
// Each wave: disjoint Wq tile [d0:d0+16) x [c0:c0+256), float4-coalesced rows.
// x_cls tile for ALL 16 batches staged in LDS. Wq read exactly once (4 MB).
__global__ __launch_bounds__(64) void qcls_partial_kernel(
    const float* __restrict__ x, const float* __restrict__ w,
    float* __restrict__ part) {
    const int ci = blockIdx.x;          // col chunk: 256 cols
    const int pi = blockIdx.y;          // d chunk: 16 rows
    const int lane = threadIdx.x;
    const int d0 = pi * 16;
    __shared__ float xs[BATCH * 16];    // xs[b*16 + dd] = x[b,0,d0+dd]
    #pragma unroll
    for (int i = lane; i < BATCH * 16; i += 64) {
        const int b = i >> 4, dd = i & 15;
        xs[i] = x[(size_t)b * SEQ * CH + d0 + dd];
    }
    __syncthreads();
    const int c = ci * 256 + lane * 4;
    float4 acc[BATCH];
    #pragma unroll
    for (int b = 0; b < BATCH; ++b) acc[b] = {0.f, 0.f, 0.f, 0.f};
    #pragma unroll 4
    for (int dd = 0; dd < 16; ++dd) {
        const float4 wv = *(const float4*)(w + (size_t)(d0 + dd) * W3 + c);
        #pragma unroll
        for (int b = 0; b < BATCH; ++b) {
            const float s = xs[b * 16 + dd];
            acc[b].x += s * wv.x; acc[b].y += s * wv.y;
            acc[b].z += s * wv.z; acc[b].w += s * wv.w;
        }
    }
    #pragma unroll
    for (int b = 0; b < BATCH; ++b)
        *(float4*)(part + (size_t)pi * BATCH * CH + b * CH + c) = acc[b];
}

// ---------------- Kernel A2: reduce 64 partials -> q_cls ----------------
__global__ __launch_bounds__(256) void qcls_reduce_kernel(
    const float* __restrict__ part, float* __restrict__ qcls) {
    const int id = blockIdx.x * 256 + threadIdx.x;   // b*1024 + c
    float s = 0.f;
    #pragma unroll 8
    for (int p = 0; p < 64; ++p) s += part[(size_t)p * BATCH * CH + id];
    qcls[id] = s;
}

// ---------------- Kernel B: v[b,d] = Wk[d,:] . q_cls[b,:] ----------------
// grid 128, block 256 (4 waves). q_cls (64 KB) staged in LDS.
__global__ __launch_bounds__(256) void v_kernel(
    const float* __restrict__ w, const float* __restrict__ qcls,
    float* __restrict__ v) {
    __shared__ float qs[BATCH * CH];   // 64 KB
    const int t = threadIdx.x;
    for (int i = t; i < BATCH * CH; i += 256) qs[i] = qcls[i];
    __syncthreads();
    const int lane = t & 63;
    const int wave = t >> 6;
    #pragma unroll
    for (int k = 0; k < 2; ++k) {
        const int d = blockIdx.x * 8 + wave * 2 + k;
        const float* wrow = w + (size_t)d * W3 + CH;    // Wk = cols [1024,2048)
        float4 wv[4];
        #pragma unroll
        for (int j = 0; j < 4; ++j)
            wv[j] = *(const float4*)(wrow + lane * 4 + j * 256);
        #pragma unroll
        for (int b = 0; b < BATCH; ++b) {
            float acc = 0.f;
            #pragma unroll
            for (int j = 0; j < 4; ++j) {
                float4 qv = *(const float4*)(&qs[b * CH + lane * 4 + j * 256]);
                acc += wv[j].x * qv.x + wv[j].y * qv.y
                     + wv[j].z * qv.z + wv[j].w * qv.w;
            }
            #pragma unroll
            for (int off = 32; off > 0; off >>= 1)
                acc += __shfl_down(acc, off, 64);
            if (lane == 0) v[b * CH + d] = acc;
        }
    }
}

// ---------------- Kernel C v2: logits streamer with v-register reuse -------
// grid (64 row-groups, 16 b), block 256 = 4 waves. Each wave: loads v[b]
// into 16 VGPRs ONCE, then streams 8 consecutive x rows (4 KB each) and
// dot-reduces. Block covers 32 contiguous rows = 128 KB contiguous HBM.
__global__ __launch_bounds__(256) void logits_kernel(
    const float* __restrict__ x, const float* __restrict__ v,
    float* __restrict__ logits) {
    const int b = blockIdx.y;
    const int g = blockIdx.x;                 // 0..63
    const int t = threadIdx.x;
    const int lane = t & 63;
    const int wave = t >> 6;
    const int n0 = g * 32 + wave * 8;         // first logit row of this wave
    const float* vrow = v + b * CH + lane * 4;
    float4 vv[4];
    #pragma unroll
    for (int j = 0; j < 4; ++j) vv[j] = *(const float4*)(vrow + j * 256);
    const float* xbase = x + ((size_t)b * SEQ + 1 + n0) * CH + lane * 4;
    float acc[8];
    #pragma unroll
    for (int r = 0; r < 8; ++r) {
        float4 x0 = *(const float4*)(xbase + (size_t)r * CH);
        float4 x1 = *(const float4*)(xbase + (size_t)r * CH + 256);
        float4 x2 = *(const float4*)(xbase + (size_t)r * CH + 512);
        float4 x3 = *(const float4*)(xbase + (size_t)r * CH + 768);
        acc[r] = x0.x * vv[0].x + x0.y * vv[0].y + x0.z * vv[0].z + x0.w * vv[0].w
               + x1.x * vv[1].x + x1.y * vv[1].y + x1.z * vv[1].z + x1.w * vv[1].w
               + x2.x * vv[2].x + x2.y * vv[2].y + x2.z * vv[2].z + x2.w * vv[2].w
               + x3.x * vv[3].x + x3.y * vv[3].y + x3.z * vv[3].z + x3.w * vv[3].w;
    }
    #pragma unroll
    for (int r = 0; r < 8; ++r) {
        #pragma unroll
        for (int off = 32; off > 0; off >>= 1)
            acc[r] += __shfl_down(acc[r], off, 64);
    }
    if (lane == 0) {
        #pragma unroll
        for (int r = 0; r < 8; ++r)
            logits[b * NOUT + n0 + r] = acc[r] * 0.03125f;  // scale = 1/32
    }
}

// ---------------- Kernel D: softmax over 2048 per batch ----------------
__global__ __launch_bounds__(256) void softmax_kernel(
    const float* __restrict__ logits, float* __restrict__ out) {
    const int b = blockIdx.x;
    const int t = threadIdx.x;
    __shared__ float sm[256];
    float val[8];
    float m = -1e30f;
    #pragma unroll
    for (int i = 0; i < 8; ++i) {
        val[i] = logits[b * NOUT + t + i * 256];
        m = fmaxf(m, val[i]);
    }
    sm[t] = m; __syncthreads();
    for (int s = 128; s > 0; s >>= 1) {
        if (t < s) sm[t] = fmaxf(sm[t], sm[t + s]);
        __syncthreads();
    }
    const float mx = sm[0];
    __syncthreads();
    float e[8];
    float sum = 0.f;
    #pragma unroll
    for (int i = 0; i < 8; ++i) { e[i] = expf(val[i] - mx); sum += e[i]; }
    sm[t] = sum; __syncthreads();
    for (int s = 128; s > 0; s >>= 1) {
        if (t < s) sm[t] += sm[t + s];
        __syncthreads();
    }
    const float inv = 1.0f / sm[0];
    #pragma unroll
    for (int i = 0; i < 8; ++i) out[b * NOUT + t + i * 256] = e[i] * inv;
}

extern "C" void kernel_launch(void* const* d_in, const int* in_sizes, int n_in,
                              void* d_out, int out_size, void* d_ws, size_t ws_size,
                              hipStream_t stream) {
    const float* x = (const float*)d_in[0];   // (16, 2049, 1024) fp32
    const float* w = (const float*)d_in[1];   // (1024, 3072) fp32
    float* out = (float*)d_out;               // (16, 2048) fp32
    float* ws = (float*)d_ws;

    float* part   = ws;                       // 1,048,576 floats (4 MB)
    float* qcls   = ws + 1048576;             // 16384 floats
    float* vbuf   = ws + 1048576 + 16384;     // 16384 floats
    float* logits = ws + 1048576 + 32768;     // 32768 floats

    qcls_partial_kernel<<<dim3(4, 64), 64, 0, stream>>>(x, w, part);
    qcls_reduce_kernel<<<64, 256, 0, stream>>>(part, qcls);
    v_kernel<<<128, 256, 0, stream>>>(w, qcls, vbuf);
    logits_kernel<<<dim3(64, BATCH), 256, 0, stream>>>(x, vbuf, logits);
    softmax_kernel<<<BATCH, 256, 0, stream>>>(logits, out);
}